// Round 6
// baseline (383.864 us; speedup 1.0000x reference)
//
#include <hip/hip_runtime.h>

typedef unsigned int u32;
typedef __fp16 half2_t __attribute__((ext_vector_type(2)));
typedef __fp16 half8_t __attribute__((ext_vector_type(8)));
typedef float  f32x4   __attribute__((ext_vector_type(4)));

#define DIN 128
#define DH  128
#define SEQL 512
#define NBATCH 256
#define NC  512          // 4*DH fused gate columns
#define TC  64           // timesteps per chunk
#define NCHUNK (SEQL/TC) // 8

#define LDS_HOFF 65536   // hbuf byte offset (xgT = 64 KB below it)
#define LDS_TOTAL (65536 + 512)

__device__ __forceinline__ u32 pk2(float a, float b) {
  half2_t h = __builtin_amdgcn_cvt_pkrtz(a, b);
  return __builtin_bit_cast(u32, h);
}

__device__ __forceinline__ float fexp2(float x) {
#if defined(__has_builtin) && __has_builtin(__builtin_amdgcn_exp2f)
  return __builtin_amdgcn_exp2f(x);
#else
  return __builtin_exp2f(x);
#endif
}

__device__ __forceinline__ float dot2(u32 a, u32 b, float c) {
#if defined(__has_builtin) && __has_builtin(__builtin_amdgcn_fdot2)
  return __builtin_amdgcn_fdot2(__builtin_bit_cast(half2_t, a),
                                __builtin_bit_cast(half2_t, b), c, false);
#else
  half2_t ha = __builtin_bit_cast(half2_t, a);
  half2_t hb = __builtin_bit_cast(half2_t, b);
  return c + (float)ha[0]*(float)hb[0] + (float)ha[1]*(float)hb[1];
#endif
}

#define MF(A, B, C) __builtin_amdgcn_mfma_f32_16x16x32_f16( \
    __builtin_bit_cast(half8_t, A), __builtin_bit_cast(half8_t, B), C, 0, 0, 0)

// 8 dot2s for one h-frag (uint4 A) against g/o weight frags, 4 acc chains
#define DOTQ(W_G, W_O, A) \
  pg0 = dot2((W_G).x, (A).x, pg0); po0 = dot2((W_O).x, (A).x, po0); \
  pg1 = dot2((W_G).y, (A).y, pg1); po1 = dot2((W_O).y, (A).y, po1); \
  pg0 = dot2((W_G).z, (A).z, pg0); po0 = dot2((W_O).z, (A).z, po0); \
  pg1 = dot2((W_G).w, (A).w, pg1); po1 = dot2((W_O).w, (A).w, po1);

// Pack fused weight matrices into f16-pair (k-pair) column-major images:
// wT[j][kk] = (w[2kk][j], w[2kk+1][j]),  j in [0,512), kk in [0,64)
__global__ void pack_w(const float* __restrict__ x2i, const float* __restrict__ x2f,
                       const float* __restrict__ x2g, const float* __restrict__ x2o,
                       const float* __restrict__ h2i, const float* __restrict__ h2f,
                       const float* __restrict__ h2g, const float* __restrict__ h2o,
                       u32* __restrict__ wxT, u32* __restrict__ whT) {
  int idx = blockIdx.x * blockDim.x + threadIdx.x;   // 0..32767
  if (idx >= NC * 64) return;
  int j = idx >> 6, kk = idx & 63;
  int g = j >> 7, jjj = j & 127;
  const float* wx = (g == 0) ? x2i : (g == 1) ? x2f : (g == 2) ? x2g : x2o;
  const float* wh = (g == 0) ? h2i : (g == 1) ? h2f : (g == 2) ? h2g : h2o;
  wxT[idx] = pk2(wx[(2*kk)*DH + jjj], wx[(2*kk+1)*DH + jjj]);
  whT[idx] = pk2(wh[(2*kk)*DH + jjj], wh[(2*kk+1)*DH + jjj]);
}

// LDS: xgT [512 col][128 B of t, XOR-swizzled f16] = 64 KB ; hbuf [2][128] f16
__global__ __launch_bounds__(512, 2)
void lstm_fused(
    const float* __restrict__ x, const u32* __restrict__ wxT,
    const u32* __restrict__ whT, const float* __restrict__ w_out,
    float* __restrict__ out) {
  extern __shared__ char lds[];
  char* xgT = lds;

  const int tid = threadIdx.x;
  const int b   = blockIdx.x;
  const int l   = tid & 63, wv = tid >> 6;
  const int kg  = l >> 4, r15 = l & 15;
  const int j   = wv * 16 + r15;   // hidden index this lane owns

  // Recurrence weights, col j of each gate, k aligned to A-frag slices:
  // frag[kt] = whT[(g*128+j)*64][u32 16kt+4kg .. +4]  (k in kt*32+8kg+[0,8))
  uint4 bi[4], bfr[4];   // MFMA B-frags: gates i,f
  uint4 wg[4], wo[4];    // VALU dot2 weights: gates g,o
  {
    const uint4* p0 = (const uint4*)(whT + (0 * DH + j) * 64);
    const uint4* p1 = (const uint4*)(whT + (1 * DH + j) * 64);
    const uint4* p2 = (const uint4*)(whT + (2 * DH + j) * 64);
    const uint4* p3 = (const uint4*)(whT + (3 * DH + j) * 64);
#pragma unroll
    for (int kt = 0; kt < 4; ++kt) {
      bi[kt]  = p0[kt * 4 + kg];
      bfr[kt] = p1[kt * 4 + kg];
      wg[kt]  = p2[kt * 4 + kg];
      wo[kt]  = p3[kt * 4 + kg];
    }
  }

  if (tid < 128) ((u32*)(lds + LDS_HOFF))[tid] = 0u;   // zero both h buffers
  float c = 0.f;
  u32 rdh = LDS_HOFF;          // current h (f16[128])
  u32 wrh = LDS_HOFF + 256;    // next h
  const float* xb = x + (size_t)b * SEQL * DIN;
  __syncthreads();

  for (int ch = 0; ch < NCHUNK; ++ch) {
    // ---- phase A: xg[t][col] = x_chunk @ wx via MFMA, A-frags from global ----
#pragma unroll 1
    for (int tt = 0; tt < 4; ++tt) {
      uint4 afr[4];
#pragma unroll
      for (int ko = 0; ko < 4; ++ko) {
        const float4* xp = (const float4*)(xb + (size_t)(ch*TC + tt*16 + r15)*DIN + ko*32 + kg*8);
        float4 v0 = xp[0], v1 = xp[1];
        afr[ko].x = pk2(v0.x, v0.y); afr[ko].y = pk2(v0.z, v0.w);
        afr[ko].z = pk2(v1.x, v1.y); afr[ko].w = pk2(v1.z, v1.w);
      }
#pragma unroll
      for (int nt = 0; nt < 4; ++nt) {
        int n = wv * 64 + nt * 16 + r15;
        f32x4 acc = {0.f, 0.f, 0.f, 0.f};
#pragma unroll
        for (int ko = 0; ko < 4; ++ko) {
          uint4 bf = *(const uint4*)(wxT + n*64 + ko*16 + kg*4);
          acc = MF(afr[ko], bf, acc);
        }
        // store C: col n, t0 = tt*16+kg*4 .. +4, into [col][t] XOR-swizzled
        int t0 = tt*16 + kg*4;
        u32 off = (u32)(n*128 + ((t0*2) ^ ((n & 7) << 4)));
        uint2 pw; pw.x = pk2(acc[0], acc[1]); pw.y = pk2(acc[2], acc[3]);
        *(uint2*)(xgT + off) = pw;
      }
    }
    __syncthreads();

    // ---- phase B: 64 steps; i,f on MFMA pipe, g,o on VALU dot2 pipe ----
#pragma unroll 1
    for (int m = 0; m < 8; ++m) {
      // xg for col j of each gate, timesteps [8m, 8m+8)
      half8_t xh[4];
#pragma unroll
      for (int g = 0; g < 4; ++g) {
        int cg = g * DH + j;
        xh[g] = __builtin_bit_cast(half8_t,
            *(const uint4*)(xgT + cg*128 + ((m*16) ^ ((cg & 7) << 4))));
      }
#pragma unroll
      for (int s8 = 0; s8 < 8; ++s8) {
        // h frags: shared by MFMA A-operand and VALU dots
        uint4 a0 = *(const uint4*)(lds + rdh +   0 + kg*16);
        uint4 a1 = *(const uint4*)(lds + rdh +  64 + kg*16);
        uint4 a2 = *(const uint4*)(lds + rdh + 128 + kg*16);
        uint4 a3 = *(const uint4*)(lds + rdh + 192 + kg*16);
        // VALU: g,o partials over this lane's k-slices (32 dot2, 4 chains)
        float pg0 = 0.f, pg1 = 0.f, po0 = 0.f, po1 = 0.f;
        DOTQ(wg[0], wo[0], a0)
        DOTQ(wg[1], wo[1], a1)
        DOTQ(wg[2], wo[2], a2)
        DOTQ(wg[3], wo[3], a3)
        // MFMA: i,f full-K for 16 cols (all rows identical -> in-lane result)
        f32x4 z = {0.f, 0.f, 0.f, 0.f};
        f32x4 aci = z, acf = z;
        aci = MF(a0, bi[0], aci); acf = MF(a0, bfr[0], acf);
        aci = MF(a1, bi[1], aci); acf = MF(a1, bfr[1], acf);
        aci = MF(a2, bi[2], aci); acf = MF(a2, bfr[2], acf);
        aci = MF(a3, bi[3], aci); acf = MF(a3, bfr[3], acf);
        // reduce g,o partials across the 4 kg groups (lane^16, lane^32)
        float gs = pg0 + pg1, os = po0 + po1;
        gs += __shfl_xor(gs, 16, 64); os += __shfl_xor(os, 16, 64);
        gs += __shfl_xor(gs, 32, 64); os += __shfl_xor(os, 32, 64);
        // gates + nonlinearity
        float gg = gs + (float)xh[2][s8];
        float go = os + (float)xh[3][s8];
        float sg = __builtin_fmaf(2.f,
                     __builtin_amdgcn_rcpf(1.f + fexp2(gg * -2.885390082f)), -1.f);
        float so = __builtin_amdgcn_rcpf(1.f + fexp2(go * -1.442695041f));
        float gi = aci[0] + (float)xh[0][s8];
        float gf = acf[0] + (float)xh[1][s8];
        float si = __builtin_amdgcn_rcpf(1.f + fexp2(gi * -1.442695041f));
        float sf = __builtin_amdgcn_rcpf(1.f + fexp2(gf * -1.442695041f));
        c = __builtin_fmaf(sf, c, si * sg);
        float th = __builtin_fmaf(2.f,
                     __builtin_amdgcn_rcpf(1.f + fexp2(c * -2.885390082f)), -1.f);
        float hval = so * th;
        if (l < 16) *(__fp16*)(lds + wrh + j * 2) = (__fp16)hval;
        u32 tswap = rdh; rdh = wrh; wrh = tswap;
        __syncthreads();
      }
    }
  }

  // ---- tail: out[b][n] = h_final @ w_out ----
  if (tid < DH) {
    int n = tid;
    const u32* hf = (const u32*)(lds + rdh);   // final h (f16 pairs)
    float acc = 0.f;
#pragma unroll 8
    for (int kk = 0; kk < 64; ++kk) {
      half2_t h2v = __builtin_bit_cast(half2_t, hf[kk]);
      acc = __builtin_fmaf((float)h2v[0], w_out[(2*kk)*DH + n],
            __builtin_fmaf((float)h2v[1], w_out[(2*kk+1)*DH + n], acc));
    }
    out[b * DH + n] = acc;
  }
}

extern "C" void kernel_launch(void* const* d_in, const int* in_sizes, int n_in,
                              void* d_out, int out_size, void* d_ws, size_t ws_size,
                              hipStream_t stream) {
  const float* x    = (const float*)d_in[0];
  const float* x2i  = (const float*)d_in[1];
  const float* x2f  = (const float*)d_in[2];
  const float* x2g  = (const float*)d_in[3];
  const float* x2o  = (const float*)d_in[4];
  const float* h2i  = (const float*)d_in[5];
  const float* h2f  = (const float*)d_in[6];
  const float* h2g  = (const float*)d_in[7];
  const float* h2o  = (const float*)d_in[8];
  const float* wout = (const float*)d_in[9];

  u32* wxT = (u32*)d_ws;            // 512*64*4 = 128 KB
  u32* whT = wxT + NC * 64;         // +128 KB

  (void)hipFuncSetAttribute((const void*)lstm_fused,
                            hipFuncAttributeMaxDynamicSharedMemorySize, LDS_TOTAL);

  pack_w<<<64, 512, 0, stream>>>(x2i, x2f, x2g, x2o, h2i, h2f, h2g, h2o, wxT, whT);
  lstm_fused<<<NBATCH, 512, LDS_TOTAL, stream>>>(x, wxT, whT, wout, (float*)d_out);
}